// Round 4
// baseline (337.258 us; speedup 1.0000x reference)
//
#include <hip/hip_runtime.h>
#include <hip/hip_bf16.h>
#include <math.h>

constexpr int kN = 10000;   // nodes
constexpr int kE = 160000;  // edges
constexpr float kSlope = 0.2f;

typedef short v8s __attribute__((ext_vector_type(8)));
typedef float f32x4 __attribute__((ext_vector_type(4)));
typedef unsigned short ushort_t;

__device__ __forceinline__ float lrelu(float x) { return x > 0.f ? x : kSlope * x; }
__device__ __forceinline__ float elu_f(float x) { return x > 0.f ? x : (__expf(x) - 1.f); }
__device__ __forceinline__ float b2f(ushort_t u) {
    return __uint_as_float(((unsigned)u) << 16);
}
__device__ __forceinline__ float bl(unsigned u) { return __uint_as_float(u << 16); }
__device__ __forceinline__ float bh(unsigned u) { return __uint_as_float(u & 0xffff0000u); }
__device__ __forceinline__ ushort_t f2b(float f) {   // RNE f32->bf16
    unsigned u = __float_as_uint(f);
    return (ushort_t)((u + 0x7FFFu + ((u >> 16) & 1u)) >> 16);
}

// ---------------- dtype detection + deg/cnt zeroing (one launch) ----------------
__global__ void detect_zero(const void* __restrict__ x, const void* __restrict__ dsti,
                            int* __restrict__ flags, int* __restrict__ deg) {
    if (blockIdx.x == 0) {
        __shared__ int sb[2];
        int tid = threadIdx.x;
        if (tid == 0) { sb[0] = 0; sb[1] = 0; }
        __syncthreads();
        const ushort_t* xb = (const ushort_t*)x;
        int big = 0;
        for (int i = tid; i < 4096; i += 256) {
            float v = b2f(xb[i]);
            if (!(fabsf(v) <= 1e4f)) big = 1;
        }
        const int* d32 = (const int*)dsti;
        int hi = 0;
        for (int i = tid; i < 4096; i += 256) hi |= d32[2 * i + 1];
        if (big) atomicOr(&sb[0], 1);
        if (hi)  atomicOr(&sb[1], 1);
        __syncthreads();
        if (tid == 0) { flags[0] = sb[0]; flags[1] = sb[1] ? 0 : 1; }
    } else {
        int i = (blockIdx.x - 1) * 256 + threadIdx.x;
        if (i < 2 * kN) deg[i] = 0;    // deg + cnt contiguous
    }
}

// ---------------- all flag-dependent prep in ONE launch ----------------
struct PrepArgs {
    const void* sm[13];
    const void* W0; const void* W1; const void* W2; const void* Wm0; const void* Wm1;
    const void* X; const void* srcIn; const void* dstIn;
    float* smallb;
    ushort_t* W0T; ushort_t* W1T; ushort_t* W2T; ushort_t* PQT; ushort_t* Wm1T;
    ushort_t* Xb;
    int* nsrc; int* ndst; int* deg;
    const int* flags;
};
// segments: 4865 | 131072 | 262144 | 262144 | 32768 | 8192 | 2560000 | 320000
constexpr int kPrepTotal = 4865 + 131072 + 262144 + 262144 + 32768 + 8192 + 2560000 + 320000;

__global__ void prep_all(PrepArgs a) {
    int i = blockIdx.x * 256 + threadIdx.x;
    if (i >= kPrepTotal) return;
    const int f32in = a.flags[0];
    auto cv = [&](const void* p, int idx) -> ushort_t {
        return f32in ? f2b(((const float*)p)[idx]) : ((const ushort_t*)p)[idx];
    };
    if (i < 4865) {   // small f32 tensors
        int seg, offi;
        if (i < 4608)      { seg = i >> 9; offi = i & 511; }
        else if (i < 4736) { seg = 9;  offi = i - 4608; }
        else if (i < 4800) { seg = 10; offi = i - 4736; }
        else if (i < 4864) { seg = 11; offi = i - 4800; }
        else               { seg = 12; offi = 0; }
        a.smallb[i] = f32in ? ((const float*)a.sm[seg])[offi]
                            : b2f(((const ushort_t*)a.sm[seg])[offi]);
        return;
    }
    i -= 4865;
    if (i < 131072) {   // W0T [512][256]
        int n = i >> 8, k = i & 255;
        a.W0T[i] = cv(a.W0, k * 512 + n);
        return;
    }
    i -= 131072;
    if (i < 262144) {   // W1T [512][512]
        int n = i >> 9, k = i & 511;
        a.W1T[i] = cv(a.W1, k * 512 + n);
        return;
    }
    i -= 262144;
    if (i < 262144) {   // W2T [512][512]
        int n = i >> 9, k = i & 511;
        a.W2T[i] = cv(a.W2, k * 512 + n);
        return;
    }
    i -= 262144;
    if (i < 32768) {    // PQT [256][128]
        int n = i >> 7, k = i & 127;
        a.PQT[i] = cv(a.Wm0, (k + ((n < 128) ? 0 : 128)) * 128 + (n & 127));
        return;
    }
    i -= 32768;
    if (i < 8192) {     // Wm1T [64][128]
        int n = i >> 7, k = i & 127;
        a.Wm1T[i] = cv(a.Wm1, k * 64 + n);
        return;
    }
    i -= 8192;
    if (i < 2560000) {  // Xb bf16 (only when input f32; else consumers read d_in[0])
        if (f32in) a.Xb[i] = f2b(((const float*)a.X)[i]);
        return;
    }
    i -= 2560000;
    {                   // index normalize + degree count
        const void* in = (i < kE) ? a.srcIn : a.dstIn;
        int j = (i < kE) ? i : i - kE;
        int v = a.flags[1] ? (int)((const long long*)in)[j] : ((const int*)in)[j];
        v = ((unsigned)v < (unsigned)kN) ? v : 0;
        if (i < kE) a.nsrc[j] = v;
        else { a.ndst[j] = v; atomicAdd(&a.deg[v], 1); }
    }
}

// ---------------- CSR build + wl0/wr0 = W0_h @ al0_h / ar0_h ----------------
__global__ __launch_bounds__(1024) void scan_off(const int* __restrict__ deg,
                                                 int* __restrict__ off, int n,
                                                 const ushort_t* __restrict__ W0T,
                                                 const float* __restrict__ al0,
                                                 const float* __restrict__ ar0,
                                                 float* __restrict__ wl0,
                                                 float* __restrict__ wr0) {
    __shared__ int s[1024];
    int tid = threadIdx.x;
    int per = (n + 1023) >> 10;
    int base = tid * per;
    int sum = 0;
    for (int i = 0; i < per; ++i) { int j = base + i; if (j < n) sum += deg[j]; }
    s[tid] = sum;
    __syncthreads();
    for (int d = 1; d < 1024; d <<= 1) {
        int v = (tid >= d) ? s[tid - d] : 0;
        __syncthreads();
        s[tid] += v;
        __syncthreads();
    }
    int run = (tid > 0) ? s[tid - 1] : 0;
    for (int i = 0; i < per; ++i) {
        int j = base + i;
        if (j < n) { off[j] = run; run += deg[j]; }
    }
    if (tid == 0) off[n] = s[1023];
    // wl0[h][k] = sum_d W0[k][h*128+d]*al0[h][d]  (W0T[n][k], n = h*128+d)
    {
        int h = tid >> 8, k = tid & 255;
        const ushort_t* wp = W0T + (size_t)(h * 128) * 256 + k;
        float accl = 0.f, accr = 0.f;
        for (int d = 0; d < 128; ++d) {
            float wv = b2f(wp[(size_t)d * 256]);
            accl += wv * al0[h * 128 + d];
            accr += wv * ar0[h * 128 + d];
        }
        wl0[tid] = accl;
        wr0[tid] = accr;
    }
}

// fill CSR (blocks 0..624) + el0/er0 = x . wl0/wr0 (blocks 625..3124)
constexpr int kFillBlocks = 625;   // 625*256 == kE
__global__ void fill_csr(const int* __restrict__ src, const int* __restrict__ dst,
                         const int* __restrict__ off, int* __restrict__ cnt,
                         int* __restrict__ ss, int* __restrict__ eid,
                         int* __restrict__ dpos, int n,
                         const ushort_t* __restrict__ xb, const void* __restrict__ xraw,
                         const int* __restrict__ gflags,
                         const float* __restrict__ wl0, const float* __restrict__ wr0,
                         float* __restrict__ el0, float* __restrict__ er0) {
    if (blockIdx.x < kFillBlocks) {
        int i = blockIdx.x * 256 + threadIdx.x;
        if (i < n) {
            int d = dst[i];
            int pos = off[d] + atomicAdd(&cnt[d], 1);
            if (pos < kE) { ss[pos] = src[i]; eid[pos] = i; dpos[pos] = d; }
        }
        return;
    }
    const int node = (blockIdx.x - kFillBlocks) * 4 + (threadIdx.x >> 6);
    const int lane = threadIdx.x & 63;
    if (node >= kN) return;
    const ushort_t* xeff = (gflags[0] == 0) ? (const ushort_t*)xraw : xb;
    ushort4 x4 = *(const ushort4*)(xeff + (size_t)node * 256 + lane * 4);
    float xv[4] = {b2f(x4.x), b2f(x4.y), b2f(x4.z), b2f(x4.w)};
    float ep[4] = {}, rp[4] = {};
#pragma unroll
    for (int h = 0; h < 4; ++h) {
        const float* wlh = wl0 + h * 256 + lane * 4;
        const float* wrh = wr0 + h * 256 + lane * 4;
#pragma unroll
        for (int i = 0; i < 4; ++i) { ep[h] += xv[i] * wlh[i]; rp[h] += xv[i] * wrh[i]; }
    }
#pragma unroll
    for (int m = 1; m < 64; m <<= 1) {
#pragma unroll
        for (int h = 0; h < 4; ++h) {
            ep[h] += __shfl_xor(ep[h], m);
            rp[h] += __shfl_xor(rp[h], m);
        }
    }
    if (lane == 0) {
#pragma unroll
        for (int h = 0; h < 4; ++h) {
            el0[node * 4 + h] = ep[h];
            er0[node * 4 + h] = rp[h];
        }
    }
}

// ---------------- layer-0 RAW aggregation: gather 256-dim x rows (512B/edge) ----------
// araw[node][h][0:256] = (sum_e alpha_e,h * x[src_e]) as bf16; alpha = softmax-by-sum.
__global__ __launch_bounds__(256) void gat_agg_raw(const ushort_t* __restrict__ xb,
                                                   const void* __restrict__ xraw,
                                                   const int* __restrict__ gflags,
                                                   const float* __restrict__ el,
                                                   const float* __restrict__ er,
                                                   const int* __restrict__ off,
                                                   const int* __restrict__ ss,
                                                   ushort_t* __restrict__ araw) {
    const int node = blockIdx.x * 4 + (threadIdx.x >> 6);
    const int lane = threadIdx.x & 63;
    if (node >= kN) return;
    const ushort_t* xeff = (gflags[0] == 0) ? (const ushort_t*)xraw : xb;
    const int off0 = off[node];
    const int deg = off[node + 1] - off0;
    float4 er4 = *(const float4*)(er + node * 4);
    const ushort_t* xcol = xeff + lane * 4;

    float den[4] = {};
    float acc[4][4] = {};
    if (deg > 0) {
        float4 e0[4], e1[4];
        ushort4 x0[4], x1[4];
        auto LD = [&](int bj, float4* ev, ushort4* xv) {
#pragma unroll
            for (int i = 0; i < 4; ++i) {
                int s = ss[off0 + min(bj + i, deg - 1)];
                ev[i] = *(const float4*)(el + s * 4);
                xv[i] = *(const ushort4*)(xcol + (size_t)s * 256);
            }
        };
        auto CONS = [&](int bj, const float4* ev, const ushort4* xv) {
#pragma unroll
            for (int i = 0; i < 4; ++i) {
                if (bj + i < deg) {
                    float w0 = __expf(lrelu(ev[i].x + er4.x));
                    float w1 = __expf(lrelu(ev[i].y + er4.y));
                    float w2 = __expf(lrelu(ev[i].z + er4.z));
                    float w3 = __expf(lrelu(ev[i].w + er4.w));
                    den[0] += w0; den[1] += w1; den[2] += w2; den[3] += w3;
                    float v0 = b2f(xv[i].x), v1 = b2f(xv[i].y);
                    float v2 = b2f(xv[i].z), v3 = b2f(xv[i].w);
                    acc[0][0] += w0 * v0; acc[0][1] += w0 * v1; acc[0][2] += w0 * v2; acc[0][3] += w0 * v3;
                    acc[1][0] += w1 * v0; acc[1][1] += w1 * v1; acc[1][2] += w1 * v2; acc[1][3] += w1 * v3;
                    acc[2][0] += w2 * v0; acc[2][1] += w2 * v1; acc[2][2] += w2 * v2; acc[2][3] += w2 * v3;
                    acc[3][0] += w3 * v0; acc[3][1] += w3 * v1; acc[3][2] += w3 * v2; acc[3][3] += w3 * v3;
                }
            }
        };
        LD(0, e0, x0);
        LD(4, e1, x1);
        for (int j = 0; j < deg; j += 8) {
            CONS(j, e0, x0);
            if (j + 8 < deg) LD(j + 8, e0, x0);
            CONS(j + 4, e1, x1);
            if (j + 12 < deg) LD(j + 12, e1, x1);
        }
    }
#pragma unroll
    for (int h = 0; h < 4; ++h) {
        float inv = 1.f / fmaxf(den[h], 1e-9f);
        ushort4 o = {f2b(acc[h][0] * inv), f2b(acc[h][1] * inv),
                     f2b(acc[h][2] * inv), f2b(acc[h][3] * inv)};
        *(ushort4*)(araw + (size_t)node * 1024 + h * 256 + lane * 4) = o;
    }
}

// ---------------- LDS-staged MFMA GEMM (R0-proven K-chunk-32 structure) ----------------
// A [M,*] bf16 row-major with row stride lda, per-col-block A offset aoff*blockIdx.x;
// WT [N,K] bf16 row-major. C [M,N] bf16.
// EMODE 0: plain store. 1: store + fused el/er (head = blockIdx.x). 2: bias+ELU store.
template <int EMODE>
__global__ __launch_bounds__(256) void gemm_mfma(const ushort_t* __restrict__ A,
                                                 const void* __restrict__ Araw,
                                                 const int* __restrict__ gflags,
                                                 const ushort_t* __restrict__ WT,
                                                 ushort_t* __restrict__ Cout,
                                                 int M, int N, int K, int lda, int aoff,
                                                 const float* __restrict__ al,
                                                 const float* __restrict__ ar,
                                                 float* __restrict__ el,
                                                 float* __restrict__ er,
                                                 const float* __restrict__ bias) {
    __shared__ __align__(16) ushort_t As[4][64][8];
    __shared__ __align__(16) ushort_t Bs[4][128][8];
    __shared__ float elred[64][2][2];
    const int t = threadIdx.x;
    const int wave = t >> 6, lane = t & 63;
    const int l16 = lane & 15, q = lane >> 4;
    const int row0 = blockIdx.y * 64, col0 = blockIdx.x * 128;
    const int wm = (wave & 1) * 32, wn = (wave >> 1) * 64;
    const int am = t >> 2, ak8 = t & 3;
    const int sw = ak8 * 4;

    const ushort_t* Aeff = A;
    if (Araw != nullptr && gflags[0] == 0) Aeff = (const ushort_t*)Araw;

    const ushort_t* aptr = Aeff + (size_t)min(row0 + am, M - 1) * lda
                           + (size_t)blockIdx.x * aoff + ak8 * 8;
    const ushort_t* bptr0 = WT + (size_t)(col0 + am) * K + ak8 * 8;
    const ushort_t* bptr1 = bptr0 + (size_t)64 * K;

    uint4 ga  = *(const uint4*)aptr;
    uint4 gb0 = *(const uint4*)bptr0;
    uint4 gb1 = *(const uint4*)bptr1;

    f32x4 acc[2][4];
#pragma unroll
    for (int mt = 0; mt < 2; ++mt)
#pragma unroll
        for (int nt = 0; nt < 4; ++nt)
#pragma unroll
            for (int r = 0; r < 4; ++r) acc[mt][nt][r] = 0.f;

    for (int k0 = 0; k0 < K; k0 += 32) {
        __syncthreads();
        *(uint4*)&As[ak8][am ^ sw][0] = ga;
        *(uint4*)&Bs[ak8][am ^ sw][0] = gb0;
        *(uint4*)&Bs[ak8][(am + 64) ^ sw][0] = gb1;
        __syncthreads();
        if (k0 + 32 < K) {
            ga  = *(const uint4*)(aptr + k0 + 32);
            gb0 = *(const uint4*)(bptr0 + k0 + 32);
            gb1 = *(const uint4*)(bptr1 + k0 + 32);
        }
        v8s af[2], bf[4];
        const int qs = q * 4;
#pragma unroll
        for (int mt = 0; mt < 2; ++mt)
            af[mt] = *(const v8s*)&As[q][(wm + mt * 16 + l16) ^ qs][0];
#pragma unroll
        for (int nt = 0; nt < 4; ++nt)
            bf[nt] = *(const v8s*)&Bs[q][(wn + nt * 16 + l16) ^ qs][0];
#pragma unroll
        for (int mt = 0; mt < 2; ++mt)
#pragma unroll
            for (int nt = 0; nt < 4; ++nt)
                acc[mt][nt] = __builtin_amdgcn_mfma_f32_16x16x32_bf16(af[mt], bf[nt],
                                                                      acc[mt][nt], 0, 0, 0);
    }
    float bv[4];
    if (EMODE == 2) {
#pragma unroll
        for (int nt = 0; nt < 4; ++nt)
            bv[nt] = bias[blockIdx.x * 128 + wn + nt * 16 + l16];
    }
#pragma unroll
    for (int mt = 0; mt < 2; ++mt)
#pragma unroll
        for (int r = 0; r < 4; ++r) {
            int row = row0 + wm + mt * 16 + q * 4 + r;
            if (row < M) {
#pragma unroll
                for (int nt = 0; nt < 4; ++nt) {
                    float vv = acc[mt][nt][r];
                    if (EMODE == 2) vv = elu_f(vv + bv[nt]);
                    Cout[(size_t)row * N + col0 + wn + nt * 16 + l16] = f2b(vv);
                }
            }
        }
    if (EMODE == 1) {
        const int head = blockIdx.x;
        float alv[4], arv[4];
#pragma unroll
        for (int nt = 0; nt < 4; ++nt) {
            alv[nt] = al[head * 128 + wn + nt * 16 + l16];
            arv[nt] = ar[head * 128 + wn + nt * 16 + l16];
        }
#pragma unroll
        for (int mt = 0; mt < 2; ++mt)
#pragma unroll
            for (int r = 0; r < 4; ++r) {
                float pel = 0.f, per = 0.f;
#pragma unroll
                for (int nt = 0; nt < 4; ++nt) {
                    pel += acc[mt][nt][r] * alv[nt];
                    per += acc[mt][nt][r] * arv[nt];
                }
                pel += __shfl_xor(pel, 1); per += __shfl_xor(per, 1);
                pel += __shfl_xor(pel, 2); per += __shfl_xor(per, 2);
                pel += __shfl_xor(pel, 4); per += __shfl_xor(per, 4);
                pel += __shfl_xor(pel, 8); per += __shfl_xor(per, 8);
                if (l16 == 0) {
                    int rl = wm + mt * 16 + q * 4 + r;
                    elred[rl][wave >> 1][0] = pel;
                    elred[rl][wave >> 1][1] = per;
                }
            }
        __syncthreads();
        if (t < 64) {
            int row = row0 + t;
            if (row < M) {
                el[row * 4 + head] = elred[t][0][0] + elred[t][1][0];
                er[row * 4 + head] = elred[t][0][1] + elred[t][1][1];
            }
        }
    }
}

// ---------------- GAT softmax + aggregation: 3-slot / 12-edge-deep pipeline ----------------
template <bool RES, bool ACT, int EPI>
__global__ __launch_bounds__(256) void gat_agg(const ushort_t* __restrict__ feat,
                                               const float* __restrict__ el,
                                               const float* __restrict__ er,
                                               const int* __restrict__ off,
                                               const int* __restrict__ ss,
                                               const ushort_t* residb,
                                               const float* __restrict__ bias,
                                               ushort_t* hl) {
    const int node = blockIdx.x * 4 + (threadIdx.x >> 6);
    const int lane = threadIdx.x & 63;
    if (node >= kN) return;
    const int off0 = off[node];
    const int deg = off[node + 1] - off0;
    float4 er4 = *(const float4*)(er + node * 4);
    const int head = lane >> 4;
    const float erh = (head == 0) ? er4.x : (head == 1) ? er4.y : (head == 2) ? er4.z : er4.w;
    const int c0 = lane * 8;
    const ushort_t* fbase = feat + c0;

    float den = 0.f;
    float acc[8] = {};
    if (deg > 0) {
        float e0[4], e1[4], e2[4];
        uint4 f0[4], f1[4], f2[4];
        auto LD = [&](int bj, float* ev, uint4* fv) {
#pragma unroll
            for (int i = 0; i < 4; ++i) {
                int s = ss[off0 + min(bj + i, deg - 1)];
                ev[i] = el[s * 4 + head];
                fv[i] = *(const uint4*)(fbase + (size_t)s * 512);
            }
        };
        auto CONS = [&](int bj, const float* ev, const uint4* fv) {
#pragma unroll
            for (int i = 0; i < 4; ++i) {
                if (bj + i < deg) {
                    float w = __expf(lrelu(ev[i] + erh));
                    den += w;
                    acc[0] += w * bl(fv[i].x); acc[1] += w * bh(fv[i].x);
                    acc[2] += w * bl(fv[i].y); acc[3] += w * bh(fv[i].y);
                    acc[4] += w * bl(fv[i].z); acc[5] += w * bh(fv[i].z);
                    acc[6] += w * bl(fv[i].w); acc[7] += w * bh(fv[i].w);
                }
            }
        };
        LD(0, e0, f0);
        LD(4, e1, f1);
        LD(8, e2, f2);
        for (int j = 0; j < deg; j += 12) {
            CONS(j, e0, f0);
            if (j + 12 < deg) LD(j + 12, e0, f0);
            CONS(j + 4, e1, f1);
            if (j + 16 < deg) LD(j + 16, e1, f1);
            CONS(j + 8, e2, f2);
            if (j + 20 < deg) LD(j + 20, e2, f2);
        }
    }
    const float inv = 1.f / fmaxf(den, 1e-9f);
    float4 b0 = *(const float4*)(bias + c0);
    float4 b1 = *(const float4*)(bias + c0 + 4);
    float v[8];
#pragma unroll
    for (int r = 0; r < 8; ++r) v[r] = acc[r] * inv;
    v[0] += b0.x; v[1] += b0.y; v[2] += b0.z; v[3] += b0.w;
    v[4] += b1.x; v[5] += b1.y; v[6] += b1.z; v[7] += b1.w;
    if (RES) {
        uint4 rv = *(const uint4*)(residb + (size_t)node * 512 + c0);
        v[0] += bl(rv.x); v[1] += bh(rv.x);
        v[2] += bl(rv.y); v[3] += bh(rv.y);
        v[4] += bl(rv.z); v[5] += bh(rv.z);
        v[6] += bl(rv.w); v[7] += bh(rv.w);
    }
    if (ACT) {
#pragma unroll
        for (int r = 0; r < 8; ++r) v[r] = elu_f(v[r]);
    }
    if (EPI == 1) {
        ushort_t* hp = hl + (size_t)node * 512 + c0;
        ushort4 h0 = {f2b(v[0]), f2b(v[1]), f2b(v[2]), f2b(v[3])};
        ushort4 h1 = {f2b(v[4]), f2b(v[5]), f2b(v[6]), f2b(v[7])};
        *(ushort4*)hp = h0;
        *(ushort4*)(hp + 4) = h1;
    }
    if (EPI == 2) {
        float m[8];
#pragma unroll
        for (int r = 0; r < 8; ++r) {
            float x = v[r] + __shfl_xor(v[r], 16);
            x += __shfl_xor(x, 32);
            m[r] = 0.25f * x;
        }
        if (lane < 16) {
            ushort_t* hp = hl + (size_t)node * 128 + lane * 8;
            ushort4 h0 = {f2b(m[0]), f2b(m[1]), f2b(m[2]), f2b(m[3])};
            ushort4 h1 = {f2b(m[4]), f2b(m[5]), f2b(m[6]), f2b(m[7])};
            *(ushort4*)hp = h0;
            *(ushort4*)(hp + 4) = h1;
        }
    }
}

// ---------------- MFMA edge MLP: LDS-free direct-fragment gather ----------------
__global__ __launch_bounds__(256) void edge_mfma(const ushort_t* __restrict__ PQb,
                                                 const float* __restrict__ bm0f,
                                                 const ushort_t* __restrict__ Wm1T,
                                                 const float* __restrict__ bm1f,
                                                 const float* __restrict__ wm2f,
                                                 const float* __restrict__ bm2f,
                                                 const int* __restrict__ ss,
                                                 const int* __restrict__ dpos,
                                                 const int* __restrict__ eid,
                                                 void* __restrict__ outv,
                                                 const int* __restrict__ flags) {
    const int t = threadIdx.x;
    const int wave = t >> 6, lane = t & 63;
    const int l16 = lane & 15, q = lane >> 4;
    const int base = blockIdx.x * 64 + wave * 16;
    const int pos = base + l16;
    const int s = ss[pos], d = dpos[pos];
    const ushort_t* prow = PQb + (size_t)s * 256;
    const ushort_t* qrow = PQb + (size_t)d * 256 + 128;

    f32x4 acc[4];
#pragma unroll
    for (int nt = 0; nt < 4; ++nt)
#pragma unroll
        for (int r = 0; r < 4; ++r) acc[nt][r] = 0.f;

#pragma unroll
    for (int ks = 0; ks < 4; ++ks) {
        const int k0 = ks * 32 + q * 8;
        uint4 pv = *(const uint4*)(prow + k0);
        uint4 qv = *(const uint4*)(qrow + k0);
        float4 bb0 = *(const float4*)(bm0f + k0);
        float4 bb1 = *(const float4*)(bm0f + k0 + 4);
        v8s a;
        a[0] = (short)f2b(fmaxf(bl(pv.x) + bl(qv.x) + bb0.x, 0.f));
        a[1] = (short)f2b(fmaxf(bh(pv.x) + bh(qv.x) + bb0.y, 0.f));
        a[2] = (short)f2b(fmaxf(bl(pv.y) + bl(qv.y) + bb0.z, 0.f));
        a[3] = (short)f2b(fmaxf(bh(pv.y) + bh(qv.y) + bb0.w, 0.f));
        a[4] = (short)f2b(fmaxf(bl(pv.z) + bl(qv.z) + bb1.x, 0.f));
        a[5] = (short)f2b(fmaxf(bh(pv.z) + bh(qv.z) + bb1.y, 0.f));
        a[6] = (short)f2b(fmaxf(bl(pv.w) + bl(qv.w) + bb1.z, 0.f));
        a[7] = (short)f2b(fmaxf(bh(pv.w) + bh(qv.w) + bb1.w, 0.f));
#pragma unroll
        for (int nt = 0; nt < 4; ++nt) {
            v8s b = *(const v8s*)(Wm1T + (size_t)(nt * 16 + l16) * 128 + k0);
            acc[nt] = __builtin_amdgcn_mfma_f32_16x16x32_bf16(a, b, acc[nt], 0, 0, 0);
        }
    }
    float b1v[4], w2v[4];
#pragma unroll
    for (int nt = 0; nt < 4; ++nt) {
        b1v[nt] = bm1f[nt * 16 + l16];
        w2v[nt] = wm2f[nt * 16 + l16];
    }
    float b2 = bm2f[0];
    const int f32out = flags[0];
#pragma unroll
    for (int r = 0; r < 4; ++r) {
        float v = 0.f;
#pragma unroll
        for (int nt = 0; nt < 4; ++nt)
            v += fmaxf(acc[nt][r] + b1v[nt], 0.f) * w2v[nt];
        v += __shfl_xor(v, 1);
        v += __shfl_xor(v, 2);
        v += __shfl_xor(v, 4);
        v += __shfl_xor(v, 8);
        if (l16 == 0) {
            int e = eid[base + q * 4 + r];
            float rr = 1.f / (1.f + __expf(-(v + b2)));
            if (f32out) ((float*)outv)[e] = rr;
            else        ((ushort_t*)outv)[e] = f2b(rr);
        }
    }
}

// ---------------- host launch ----------------
extern "C" void kernel_launch(void* const* d_in, const int* in_sizes, int n_in,
                              void* d_out, int out_size, void* d_ws, size_t ws_size,
                              hipStream_t stream) {
    (void)in_sizes; (void)n_in; (void)out_size; (void)ws_size;

    float* w = (float*)d_ws;
    size_t o = 0;
    auto alloc = [&](size_t n) { float* p = w + o; o += (n + 3) & ~size_t(3); return p; };
    float* smallb = alloc(4868);
    float* al0f = smallb + 0;    float* ar0f = smallb + 512;  float* b0f  = smallb + 1024;
    float* al1f = smallb + 1536; float* ar1f = smallb + 2048; float* b1f  = smallb + 2560;
    float* al2f = smallb + 3072; float* ar2f = smallb + 3584; float* b2f_ = smallb + 4096;
    float* bm0f = smallb + 4608; float* bm1f = smallb + 4736;
    float* wm2f = smallb + 4800; float* bm2f = smallb + 4864;
    float* wl0f = alloc(1024);
    float* wr0f = alloc(1024);
    float* elb  = alloc((size_t)kN * 4);
    float* erb  = alloc((size_t)kN * 4);
    ushort_t* Fb  = (ushort_t*)alloc((size_t)kN * 256);      // bf16 feat [10000][512]
    ushort_t* AHL = (ushort_t*)alloc((size_t)kN * 256);      // bf16 layer act [10000][512]
    ushort_t* ARW = (ushort_t*)alloc((size_t)kN * 512);      // bf16 raw agg [10000][4][256]
    ushort_t* MHb = (ushort_t*)alloc((size_t)kN * 64);       // bf16 head-mean [10000][128]
    ushort_t* Xb  = (ushort_t*)alloc((size_t)kN * 128);      // bf16 x [10000][256] (f32 path)
    ushort_t* W0T  = (ushort_t*)alloc(65536);                // [512][256]
    ushort_t* W1T  = (ushort_t*)alloc(131072);               // [512][512]
    ushort_t* W2T  = (ushort_t*)alloc(131072);               // [512][512]
    ushort_t* PQT  = (ushort_t*)alloc(16384);                // [256][128]
    ushort_t* Wm1T = (ushort_t*)alloc(4096);                 // [64][128]
    int* ip    = (int*)(w + o);
    int* flags = ip;
    int* deg   = ip + 4;
    int* cnt   = deg + kN;
    int* off   = cnt + kN;
    int* ss    = off + 10004;
    int* eid   = ss + kE;
    int* dpos  = eid + kE;
    int* nsrc  = dpos + kE;
    int* ndst  = nsrc + kE;

    ushort_t* PQb = Fb;   // bf16 [10000][256] P|Q; written after L2 agg frees Fb

    dim3 blk(256);

    // 0) flags + deg/cnt zero
    detect_zero<<<dim3(1 + (2 * kN + 255) / 256), blk, 0, stream>>>(d_in[0], d_in[2], flags, deg);

    // 1) all flag-dependent prep + index normalize + degree count
    PrepArgs a;
    const int sidx[13] = {4, 5, 6, 8, 9, 10, 12, 13, 14, 16, 18, 19, 20};
    for (int i = 0; i < 13; ++i) a.sm[i] = d_in[sidx[i]];
    a.W0 = d_in[3]; a.W1 = d_in[7]; a.W2 = d_in[11]; a.Wm0 = d_in[15]; a.Wm1 = d_in[17];
    a.X = d_in[0]; a.srcIn = d_in[1]; a.dstIn = d_in[2];
    a.smallb = smallb; a.W0T = W0T; a.W1T = W1T; a.W2T = W2T; a.PQT = PQT; a.Wm1T = Wm1T;
    a.Xb = Xb; a.nsrc = nsrc; a.ndst = ndst; a.deg = deg; a.flags = flags;
    prep_all<<<dim3((kPrepTotal + 255) / 256), blk, 0, stream>>>(a);

    // 2) CSR scan (+ wl0/wr0) + fill (+ el0/er0)
    scan_off<<<dim3(1), dim3(1024), 0, stream>>>(deg, off, kN, W0T, al0f, ar0f, wl0f, wr0f);
    fill_csr<<<dim3(kFillBlocks + (kN + 3) / 4), blk, 0, stream>>>(
        nsrc, ndst, off, cnt, ss, eid, dpos, kE,
        Xb, d_in[0], flags, wl0f, wr0f, elb, erb);

    const int gy = (kN + 63) / 64;      // 157 row tiles
    const int ga = (kN + 3) / 4;        // 2500 agg blocks

    // 3) Layer 0: aggregate RAW x per head (512B/edge), then per-head GEMM+bias+ELU
    gat_agg_raw<<<dim3(ga), blk, 0, stream>>>(Xb, d_in[0], flags, elb, erb, off, ss, ARW);
    gemm_mfma<2><<<dim3(4, gy), blk, 0, stream>>>(ARW, nullptr, flags, W0T, AHL,
                                                  kN, 512, 256, 1024, 256,
                                                  nullptr, nullptr, nullptr, nullptr, b0f);

    // 4) Layer 1 (residual, ELU): AHL @ W1, K=512; in-place bf16 resid+out
    gemm_mfma<1><<<dim3(4, gy), blk, 0, stream>>>(AHL, nullptr, flags, W1T, Fb,
                                                  kN, 512, 512, 512, 0,
                                                  al1f, ar1f, elb, erb, nullptr);
    gat_agg<true, true, 1><<<dim3(ga), blk, 0, stream>>>(Fb, elb, erb, off, ss,
                                                         AHL, b1f, AHL);

    // 5) Layer 2 (residual, no act) + fused head-mean bf16
    gemm_mfma<1><<<dim3(4, gy), blk, 0, stream>>>(AHL, nullptr, flags, W2T, Fb,
                                                  kN, 512, 512, 512, 0,
                                                  al2f, ar2f, elb, erb, nullptr);
    gat_agg<true, false, 2><<<dim3(ga), blk, 0, stream>>>(Fb, elb, erb, off, ss,
                                                          AHL, b2f_, MHb);

    // 6) PQb (bf16) = head-mean @ [Wm0_top | Wm0_bot], K=128  (PQb overlays Fb)
    gemm_mfma<0><<<dim3(2, gy), blk, 0, stream>>>(MHb, nullptr, flags, PQT, PQb,
                                                  kN, 256, 128, 128, 0,
                                                  nullptr, nullptr, nullptr, nullptr, nullptr);

    // 7) LDS-free edge MLP + sigmoid
    edge_mfma<<<dim3(kE / 64), blk, 0, stream>>>(PQb, bm0f, Wm1T, bm1f, wm2f, bm2f,
                                                 ss, dpos, eid, d_out, flags);
}

// Round 5
// 317.731 us; speedup vs baseline: 1.0615x; 1.0615x over previous
//
#include <hip/hip_runtime.h>
#include <hip/hip_bf16.h>
#include <math.h>

constexpr int kN = 10000;   // nodes
constexpr int kE = 160000;  // edges
constexpr float kSlope = 0.2f;

typedef short v8s __attribute__((ext_vector_type(8)));
typedef float f32x4 __attribute__((ext_vector_type(4)));
typedef unsigned short ushort_t;

__device__ __forceinline__ float lrelu(float x) { return x > 0.f ? x : kSlope * x; }
__device__ __forceinline__ float elu_f(float x) { return x > 0.f ? x : (__expf(x) - 1.f); }
__device__ __forceinline__ float b2f(ushort_t u) {
    return __uint_as_float(((unsigned)u) << 16);
}
__device__ __forceinline__ float bl(unsigned u) { return __uint_as_float(u << 16); }
__device__ __forceinline__ float bh(unsigned u) { return __uint_as_float(u & 0xffff0000u); }
__device__ __forceinline__ ushort_t f2b(float f) {   // RNE f32->bf16
    unsigned u = __float_as_uint(f);
    return (ushort_t)((u + 0x7FFFu + ((u >> 16) & 1u)) >> 16);
}

// ---------------- dtype detection + deg/cnt zeroing (one launch) ----------------
__global__ void detect_zero(const void* __restrict__ x, const void* __restrict__ dsti,
                            int* __restrict__ flags, int* __restrict__ deg) {
    if (blockIdx.x == 0) {
        __shared__ int sb[2];
        int tid = threadIdx.x;
        if (tid == 0) { sb[0] = 0; sb[1] = 0; }
        __syncthreads();
        const ushort_t* xb = (const ushort_t*)x;
        int big = 0;
        for (int i = tid; i < 4096; i += 256) {
            float v = b2f(xb[i]);
            if (!(fabsf(v) <= 1e4f)) big = 1;
        }
        const int* d32 = (const int*)dsti;
        int hi = 0;
        for (int i = tid; i < 4096; i += 256) hi |= d32[2 * i + 1];
        if (big) atomicOr(&sb[0], 1);
        if (hi)  atomicOr(&sb[1], 1);
        __syncthreads();
        if (tid == 0) { flags[0] = sb[0]; flags[1] = sb[1] ? 0 : 1; }
    } else {
        int i = (blockIdx.x - 1) * 256 + threadIdx.x;
        if (i < 2 * kN) deg[i] = 0;    // deg + cnt contiguous
    }
}

// ---------------- all flag-dependent prep in ONE launch (Xb segment removed) ------
struct PrepArgs {
    const void* sm[13];
    const void* W0; const void* W1; const void* W2; const void* Wm0; const void* Wm1;
    const void* srcIn; const void* dstIn;
    float* smallb;
    ushort_t* W0T; ushort_t* W1T; ushort_t* W2T; ushort_t* PQT; ushort_t* Wm1T;
    int* nsrc; int* ndst; int* deg;
    const int* flags;
};
// segments: 4865 | 131072 | 262144 | 262144 | 32768 | 8192 | 320000
constexpr int kPrepTotal = 4865 + 131072 + 262144 + 262144 + 32768 + 8192 + 320000;

__global__ void prep_all(PrepArgs a) {
    int i = blockIdx.x * 256 + threadIdx.x;
    if (i >= kPrepTotal) return;
    const int f32in = a.flags[0];
    auto cv = [&](const void* p, int idx) -> ushort_t {
        return f32in ? f2b(((const float*)p)[idx]) : ((const ushort_t*)p)[idx];
    };
    if (i < 4865) {   // small f32 tensors
        int seg, offi;
        if (i < 4608)      { seg = i >> 9; offi = i & 511; }
        else if (i < 4736) { seg = 9;  offi = i - 4608; }
        else if (i < 4800) { seg = 10; offi = i - 4736; }
        else if (i < 4864) { seg = 11; offi = i - 4800; }
        else               { seg = 12; offi = 0; }
        a.smallb[i] = f32in ? ((const float*)a.sm[seg])[offi]
                            : b2f(((const ushort_t*)a.sm[seg])[offi]);
        return;
    }
    i -= 4865;
    if (i < 131072) {   // W0T [512][256]
        int n = i >> 8, k = i & 255;
        a.W0T[i] = cv(a.W0, k * 512 + n);
        return;
    }
    i -= 131072;
    if (i < 262144) {   // W1T [512][512]
        int n = i >> 9, k = i & 511;
        a.W1T[i] = cv(a.W1, k * 512 + n);
        return;
    }
    i -= 262144;
    if (i < 262144) {   // W2T [512][512]
        int n = i >> 9, k = i & 511;
        a.W2T[i] = cv(a.W2, k * 512 + n);
        return;
    }
    i -= 262144;
    if (i < 32768) {    // PQT [256][128]
        int n = i >> 7, k = i & 127;
        a.PQT[i] = cv(a.Wm0, (k + ((n < 128) ? 0 : 128)) * 128 + (n & 127));
        return;
    }
    i -= 32768;
    if (i < 8192) {     // Wm1T [64][128]
        int n = i >> 7, k = i & 127;
        a.Wm1T[i] = cv(a.Wm1, k * 64 + n);
        return;
    }
    i -= 8192;
    {                   // index normalize + degree count
        const void* in = (i < kE) ? a.srcIn : a.dstIn;
        int j = (i < kE) ? i : i - kE;
        int v = a.flags[1] ? (int)((const long long*)in)[j] : ((const int*)in)[j];
        v = ((unsigned)v < (unsigned)kN) ? v : 0;
        if (i < kE) a.nsrc[j] = v;
        else { a.ndst[j] = v; atomicAdd(&a.deg[v], 1); }
    }
}

// ---------------- CSR build ----------------
__global__ __launch_bounds__(1024) void scan_off(const int* __restrict__ deg,
                                                 int* __restrict__ off, int n) {
    __shared__ int s[1024];
    int tid = threadIdx.x;
    int per = (n + 1023) >> 10;
    int base = tid * per;
    int sum = 0;
    for (int i = 0; i < per; ++i) { int j = base + i; if (j < n) sum += deg[j]; }
    s[tid] = sum;
    __syncthreads();
    for (int d = 1; d < 1024; d <<= 1) {
        int v = (tid >= d) ? s[tid - d] : 0;
        __syncthreads();
        s[tid] += v;
        __syncthreads();
    }
    int run = (tid > 0) ? s[tid - 1] : 0;
    for (int i = 0; i < per; ++i) {
        int j = base + i;
        if (j < n) { off[j] = run; run += deg[j]; }
    }
    if (tid == 0) off[n] = s[1023];
}

__global__ void fill_csr(const int* __restrict__ src, const int* __restrict__ dst,
                         const int* __restrict__ off, int* __restrict__ cnt,
                         int* __restrict__ ss, int* __restrict__ eid,
                         int* __restrict__ dpos, int n) {
    int i = blockIdx.x * 256 + threadIdx.x;
    if (i < n) {
        int d = dst[i];
        int pos = off[d] + atomicAdd(&cnt[d], 1);
        if (pos < kE) { ss[pos] = src[i]; eid[pos] = i; dpos[pos] = d; }
    }
}

// ---------------- LDS-staged MFMA GEMM (R0-proven K-chunk-32 structure) ----------------
// A [M,K] row-major: bf16, or f32 when (f32sel && gflags[0]) -> converted in-register
// during staging (bit-identical to the old prep-pass conversion).
// WT [N,K] bf16 row-major. C [M,N] bf16.
// ELER: N==512, blockIdx.x == head; fused el/er from f32 accumulators.
template <bool ELER>
__global__ __launch_bounds__(256) void gemm_mfma(const void* __restrict__ A,
                                                 const int* __restrict__ gflags,
                                                 int f32sel,
                                                 const ushort_t* __restrict__ WT,
                                                 ushort_t* __restrict__ Cout,
                                                 int M, int N, int K,
                                                 const float* __restrict__ al,
                                                 const float* __restrict__ ar,
                                                 float* __restrict__ el,
                                                 float* __restrict__ er) {
    __shared__ __align__(16) ushort_t As[4][64][8];
    __shared__ __align__(16) ushort_t Bs[4][128][8];
    __shared__ float elred[64][2][2];
    const int t = threadIdx.x;
    const int wave = t >> 6, lane = t & 63;
    const int l16 = lane & 15, q = lane >> 4;
    const int row0 = blockIdx.y * 64, col0 = blockIdx.x * 128;
    const int wm = (wave & 1) * 32, wn = (wave >> 1) * 64;
    const int am = t >> 2, ak8 = t & 3;
    const int sw = ak8 * 4;

    const int f32a = f32sel && gflags[0];
    const size_t arow = (size_t)min(row0 + am, M - 1) * K + ak8 * 8;
    const ushort_t* aB = (const ushort_t*)A + arow;
    const float*    aF = (const float*)A + arow;
    const ushort_t* bptr0 = WT + (size_t)(col0 + am) * K + ak8 * 8;
    const ushort_t* bptr1 = bptr0 + (size_t)64 * K;

    auto loadA = [&](int k0) -> uint4 {
        if (!f32a) return *(const uint4*)(aB + k0);
        float4 f0 = *(const float4*)(aF + k0);
        float4 f1 = *(const float4*)(aF + k0 + 4);
        uint4 r;
        r.x = (unsigned)f2b(f0.x) | ((unsigned)f2b(f0.y) << 16);
        r.y = (unsigned)f2b(f0.z) | ((unsigned)f2b(f0.w) << 16);
        r.z = (unsigned)f2b(f1.x) | ((unsigned)f2b(f1.y) << 16);
        r.w = (unsigned)f2b(f1.z) | ((unsigned)f2b(f1.w) << 16);
        return r;
    };

    uint4 ga  = loadA(0);
    uint4 gb0 = *(const uint4*)bptr0;
    uint4 gb1 = *(const uint4*)bptr1;

    f32x4 acc[2][4];
#pragma unroll
    for (int mt = 0; mt < 2; ++mt)
#pragma unroll
        for (int nt = 0; nt < 4; ++nt)
#pragma unroll
            for (int r = 0; r < 4; ++r) acc[mt][nt][r] = 0.f;

    for (int k0 = 0; k0 < K; k0 += 32) {
        __syncthreads();
        *(uint4*)&As[ak8][am ^ sw][0] = ga;
        *(uint4*)&Bs[ak8][am ^ sw][0] = gb0;
        *(uint4*)&Bs[ak8][(am + 64) ^ sw][0] = gb1;
        __syncthreads();
        if (k0 + 32 < K) {
            ga  = loadA(k0 + 32);
            gb0 = *(const uint4*)(bptr0 + k0 + 32);
            gb1 = *(const uint4*)(bptr1 + k0 + 32);
        }
        v8s af[2], bf[4];
        const int qs = q * 4;
#pragma unroll
        for (int mt = 0; mt < 2; ++mt)
            af[mt] = *(const v8s*)&As[q][(wm + mt * 16 + l16) ^ qs][0];
#pragma unroll
        for (int nt = 0; nt < 4; ++nt)
            bf[nt] = *(const v8s*)&Bs[q][(wn + nt * 16 + l16) ^ qs][0];
#pragma unroll
        for (int mt = 0; mt < 2; ++mt)
#pragma unroll
            for (int nt = 0; nt < 4; ++nt)
                acc[mt][nt] = __builtin_amdgcn_mfma_f32_16x16x32_bf16(af[mt], bf[nt],
                                                                      acc[mt][nt], 0, 0, 0);
    }
#pragma unroll
    for (int mt = 0; mt < 2; ++mt)
#pragma unroll
        for (int r = 0; r < 4; ++r) {
            int row = row0 + wm + mt * 16 + q * 4 + r;
            if (row < M) {
#pragma unroll
                for (int nt = 0; nt < 4; ++nt)
                    Cout[(size_t)row * N + col0 + wn + nt * 16 + l16] = f2b(acc[mt][nt][r]);
            }
        }
    if (ELER) {
        const int head = blockIdx.x;
        float alv[4], arv[4];
#pragma unroll
        for (int nt = 0; nt < 4; ++nt) {
            alv[nt] = al[head * 128 + wn + nt * 16 + l16];
            arv[nt] = ar[head * 128 + wn + nt * 16 + l16];
        }
#pragma unroll
        for (int mt = 0; mt < 2; ++mt)
#pragma unroll
            for (int r = 0; r < 4; ++r) {
                float pel = 0.f, per = 0.f;
#pragma unroll
                for (int nt = 0; nt < 4; ++nt) {
                    pel += acc[mt][nt][r] * alv[nt];
                    per += acc[mt][nt][r] * arv[nt];
                }
                pel += __shfl_xor(pel, 1); per += __shfl_xor(per, 1);
                pel += __shfl_xor(pel, 2); per += __shfl_xor(per, 2);
                pel += __shfl_xor(pel, 4); per += __shfl_xor(per, 4);
                pel += __shfl_xor(pel, 8); per += __shfl_xor(per, 8);
                if (l16 == 0) {
                    int rl = wm + mt * 16 + q * 4 + r;
                    elred[rl][wave >> 1][0] = pel;
                    elred[rl][wave >> 1][1] = per;
                }
            }
        __syncthreads();
        if (t < 64) {
            int row = row0 + t;
            if (row < M) {
                el[row * 4 + head] = elred[t][0][0] + elred[t][1][0];
                er[row * 4 + head] = elred[t][0][1] + elred[t][1][1];
            }
        }
    }
}

// ---------------- GAT softmax + aggregation: 3-slot / 12-edge-deep pipeline ----------------
// softmax = (sum e*f)/(sum e); feat bf16; resid bf16 (may alias hl).
// EPI 1: write bf16 [node][512]; EPI 2: write head-mean bf16 [node][128].
template <bool RES, bool ACT, int EPI>
__global__ __launch_bounds__(256) void gat_agg(const ushort_t* __restrict__ feat,
                                               const float* __restrict__ el,
                                               const float* __restrict__ er,
                                               const int* __restrict__ off,
                                               const int* __restrict__ ss,
                                               const ushort_t* residb,
                                               const float* __restrict__ bias,
                                               ushort_t* hl) {
    const int node = blockIdx.x * 4 + (threadIdx.x >> 6);
    const int lane = threadIdx.x & 63;
    if (node >= kN) return;
    const int off0 = off[node];
    const int deg = off[node + 1] - off0;
    float4 er4 = *(const float4*)(er + node * 4);
    const int head = lane >> 4;
    const float erh = (head == 0) ? er4.x : (head == 1) ? er4.y : (head == 2) ? er4.z : er4.w;
    const int c0 = lane * 8;
    const ushort_t* fbase = feat + c0;

    float den = 0.f;
    float acc[8] = {};
    if (deg > 0) {
        float e0[4], e1[4], e2[4];
        uint4 f0[4], f1[4], f2[4];
        auto LD = [&](int bj, float* ev, uint4* fv) {
#pragma unroll
            for (int i = 0; i < 4; ++i) {
                int s = ss[off0 + min(bj + i, deg - 1)];
                ev[i] = el[s * 4 + head];
                fv[i] = *(const uint4*)(fbase + (size_t)s * 512);
            }
        };
        auto CONS = [&](int bj, const float* ev, const uint4* fv) {
#pragma unroll
            for (int i = 0; i < 4; ++i) {
                if (bj + i < deg) {
                    float w = __expf(lrelu(ev[i] + erh));
                    den += w;
                    acc[0] += w * bl(fv[i].x); acc[1] += w * bh(fv[i].x);
                    acc[2] += w * bl(fv[i].y); acc[3] += w * bh(fv[i].y);
                    acc[4] += w * bl(fv[i].z); acc[5] += w * bh(fv[i].z);
                    acc[6] += w * bl(fv[i].w); acc[7] += w * bh(fv[i].w);
                }
            }
        };
        LD(0, e0, f0);
        LD(4, e1, f1);
        LD(8, e2, f2);
        for (int j = 0; j < deg; j += 12) {
            CONS(j, e0, f0);
            if (j + 12 < deg) LD(j + 12, e0, f0);
            CONS(j + 4, e1, f1);
            if (j + 16 < deg) LD(j + 16, e1, f1);
            CONS(j + 8, e2, f2);
            if (j + 20 < deg) LD(j + 20, e2, f2);
        }
    }
    const float inv = 1.f / fmaxf(den, 1e-9f);
    float4 b0 = *(const float4*)(bias + c0);
    float4 b1 = *(const float4*)(bias + c0 + 4);
    float v[8];
#pragma unroll
    for (int r = 0; r < 8; ++r) v[r] = acc[r] * inv;
    v[0] += b0.x; v[1] += b0.y; v[2] += b0.z; v[3] += b0.w;
    v[4] += b1.x; v[5] += b1.y; v[6] += b1.z; v[7] += b1.w;
    if (RES) {
        uint4 rv = *(const uint4*)(residb + (size_t)node * 512 + c0);
        v[0] += bl(rv.x); v[1] += bh(rv.x);
        v[2] += bl(rv.y); v[3] += bh(rv.y);
        v[4] += bl(rv.z); v[5] += bh(rv.z);
        v[6] += bl(rv.w); v[7] += bh(rv.w);
    }
    if (ACT) {
#pragma unroll
        for (int r = 0; r < 8; ++r) v[r] = elu_f(v[r]);
    }
    if (EPI == 1) {
        ushort_t* hp = hl + (size_t)node * 512 + c0;
        ushort4 h0 = {f2b(v[0]), f2b(v[1]), f2b(v[2]), f2b(v[3])};
        ushort4 h1 = {f2b(v[4]), f2b(v[5]), f2b(v[6]), f2b(v[7])};
        *(ushort4*)hp = h0;
        *(ushort4*)(hp + 4) = h1;
    }
    if (EPI == 2) {
        float m[8];
#pragma unroll
        for (int r = 0; r < 8; ++r) {
            float x = v[r] + __shfl_xor(v[r], 16);
            x += __shfl_xor(x, 32);
            m[r] = 0.25f * x;
        }
        if (lane < 16) {
            ushort_t* hp = hl + (size_t)node * 128 + lane * 8;
            ushort4 h0 = {f2b(m[0]), f2b(m[1]), f2b(m[2]), f2b(m[3])};
            ushort4 h1 = {f2b(m[4]), f2b(m[5]), f2b(m[6]), f2b(m[7])};
            *(ushort4*)hp = h0;
            *(ushort4*)(hp + 4) = h1;
        }
    }
}

// ---------------- MFMA edge MLP: LDS-free direct-fragment gather ----------------
__global__ __launch_bounds__(256) void edge_mfma(const ushort_t* __restrict__ PQb,
                                                 const float* __restrict__ bm0f,
                                                 const ushort_t* __restrict__ Wm1T,
                                                 const float* __restrict__ bm1f,
                                                 const float* __restrict__ wm2f,
                                                 const float* __restrict__ bm2f,
                                                 const int* __restrict__ ss,
                                                 const int* __restrict__ dpos,
                                                 const int* __restrict__ eid,
                                                 void* __restrict__ outv,
                                                 const int* __restrict__ flags) {
    const int t = threadIdx.x;
    const int wave = t >> 6, lane = t & 63;
    const int l16 = lane & 15, q = lane >> 4;
    const int base = blockIdx.x * 64 + wave * 16;
    const int pos = base + l16;
    const int s = ss[pos], d = dpos[pos];
    const ushort_t* prow = PQb + (size_t)s * 256;
    const ushort_t* qrow = PQb + (size_t)d * 256 + 128;

    f32x4 acc[4];
#pragma unroll
    for (int nt = 0; nt < 4; ++nt)
#pragma unroll
        for (int r = 0; r < 4; ++r) acc[nt][r] = 0.f;

#pragma unroll
    for (int ks = 0; ks < 4; ++ks) {
        const int k0 = ks * 32 + q * 8;
        uint4 pv = *(const uint4*)(prow + k0);
        uint4 qv = *(const uint4*)(qrow + k0);
        float4 bb0 = *(const float4*)(bm0f + k0);
        float4 bb1 = *(const float4*)(bm0f + k0 + 4);
        v8s a;
        a[0] = (short)f2b(fmaxf(bl(pv.x) + bl(qv.x) + bb0.x, 0.f));
        a[1] = (short)f2b(fmaxf(bh(pv.x) + bh(qv.x) + bb0.y, 0.f));
        a[2] = (short)f2b(fmaxf(bl(pv.y) + bl(qv.y) + bb0.z, 0.f));
        a[3] = (short)f2b(fmaxf(bh(pv.y) + bh(qv.y) + bb0.w, 0.f));
        a[4] = (short)f2b(fmaxf(bl(pv.z) + bl(qv.z) + bb1.x, 0.f));
        a[5] = (short)f2b(fmaxf(bh(pv.z) + bh(qv.z) + bb1.y, 0.f));
        a[6] = (short)f2b(fmaxf(bl(pv.w) + bl(qv.w) + bb1.z, 0.f));
        a[7] = (short)f2b(fmaxf(bh(pv.w) + bh(qv.w) + bb1.w, 0.f));
#pragma unroll
        for (int nt = 0; nt < 4; ++nt) {
            v8s b = *(const v8s*)(Wm1T + (size_t)(nt * 16 + l16) * 128 + k0);
            acc[nt] = __builtin_amdgcn_mfma_f32_16x16x32_bf16(a, b, acc[nt], 0, 0, 0);
        }
    }
    float b1v[4], w2v[4];
#pragma unroll
    for (int nt = 0; nt < 4; ++nt) {
        b1v[nt] = bm1f[nt * 16 + l16];
        w2v[nt] = wm2f[nt * 16 + l16];
    }
    float b2 = bm2f[0];
    const int f32out = flags[0];
#pragma unroll
    for (int r = 0; r < 4; ++r) {
        float v = 0.f;
#pragma unroll
        for (int nt = 0; nt < 4; ++nt)
            v += fmaxf(acc[nt][r] + b1v[nt], 0.f) * w2v[nt];
        v += __shfl_xor(v, 1);
        v += __shfl_xor(v, 2);
        v += __shfl_xor(v, 4);
        v += __shfl_xor(v, 8);
        if (l16 == 0) {
            int e = eid[base + q * 4 + r];
            float rr = 1.f / (1.f + __expf(-(v + b2)));
            if (f32out) ((float*)outv)[e] = rr;
            else        ((ushort_t*)outv)[e] = f2b(rr);
        }
    }
}

// ---------------- host launch ----------------
extern "C" void kernel_launch(void* const* d_in, const int* in_sizes, int n_in,
                              void* d_out, int out_size, void* d_ws, size_t ws_size,
                              hipStream_t stream) {
    (void)in_sizes; (void)n_in; (void)out_size; (void)ws_size;

    float* w = (float*)d_ws;
    size_t o = 0;
    auto alloc = [&](size_t n) { float* p = w + o; o += (n + 3) & ~size_t(3); return p; };
    float* smallb = alloc(4868);
    float* al0f = smallb + 0;    float* ar0f = smallb + 512;  float* b0f  = smallb + 1024;
    float* al1f = smallb + 1536; float* ar1f = smallb + 2048; float* b1f  = smallb + 2560;
    float* al2f = smallb + 3072; float* ar2f = smallb + 3584; float* b2f_ = smallb + 4096;
    float* bm0f = smallb + 4608; float* bm1f = smallb + 4736;
    float* wm2f = smallb + 4800; float* bm2f = smallb + 4864;
    float* elb  = alloc((size_t)kN * 4);
    float* erb  = alloc((size_t)kN * 4);
    ushort_t* Fb  = (ushort_t*)alloc((size_t)kN * 256);      // bf16 feat [10000][512]
    ushort_t* AHL = (ushort_t*)alloc((size_t)kN * 256);      // bf16 layer act [10000][512]
    ushort_t* MHb = (ushort_t*)alloc((size_t)kN * 64);       // bf16 head-mean [10000][128]
    ushort_t* W0T  = (ushort_t*)alloc(65536);                // [512][256]
    ushort_t* W1T  = (ushort_t*)alloc(131072);               // [512][512]
    ushort_t* W2T  = (ushort_t*)alloc(131072);               // [512][512]
    ushort_t* PQT  = (ushort_t*)alloc(16384);                // [256][128]
    ushort_t* Wm1T = (ushort_t*)alloc(4096);                 // [64][128]
    int* ip    = (int*)(w + o);
    int* flags = ip;
    int* deg   = ip + 4;
    int* cnt   = deg + kN;
    int* off   = cnt + kN;
    int* ss    = off + 10004;
    int* eid   = ss + kE;
    int* dpos  = eid + kE;
    int* nsrc  = dpos + kE;
    int* ndst  = nsrc + kE;

    ushort_t* PQb = Fb;   // bf16 [10000][256] P|Q; written after L2 agg frees Fb

    dim3 blk(256);

    // 0) flags + deg/cnt zero
    detect_zero<<<dim3(1 + (2 * kN + 255) / 256), blk, 0, stream>>>(d_in[0], d_in[2], flags, deg);

    // 1) all flag-dependent prep + index normalize + degree count (no Xb pass)
    PrepArgs a;
    const int sidx[13] = {4, 5, 6, 8, 9, 10, 12, 13, 14, 16, 18, 19, 20};
    for (int i = 0; i < 13; ++i) a.sm[i] = d_in[sidx[i]];
    a.W0 = d_in[3]; a.W1 = d_in[7]; a.W2 = d_in[11]; a.Wm0 = d_in[15]; a.Wm1 = d_in[17];
    a.srcIn = d_in[1]; a.dstIn = d_in[2];
    a.smallb = smallb; a.W0T = W0T; a.W1T = W1T; a.W2T = W2T; a.PQT = PQT; a.Wm1T = Wm1T;
    a.nsrc = nsrc; a.ndst = ndst; a.deg = deg; a.flags = flags;
    prep_all<<<dim3((kPrepTotal + 255) / 256), blk, 0, stream>>>(a);

    // 2) CSR scan + fill
    scan_off<<<dim3(1), dim3(1024), 0, stream>>>(deg, off, kN);
    fill_csr<<<dim3((kE + 255) / 256), blk, 0, stream>>>(nsrc, ndst, off, cnt, ss, eid, dpos, kE);

    const int gy = (kN + 63) / 64;      // 157 row tiles
    const int ga = (kN + 3) / 4;        // 2500 agg blocks

    // 3) Layer 0: Fb = x @ W0 (+ fused el/er); A = d_in[0], f32->bf16 in staging
    gemm_mfma<true><<<dim3(4, gy), blk, 0, stream>>>(d_in[0], flags, 1, W0T, Fb,
                                                     kN, 512, 256, al0f, ar0f, elb, erb);
    gat_agg<false, true, 1><<<dim3(ga), blk, 0, stream>>>(Fb, elb, erb, off, ss,
                                                          nullptr, b0f, AHL);

    // 4) Layer 1 (residual, ELU): AHL @ W1, K=512; in-place bf16 resid+out
    gemm_mfma<true><<<dim3(4, gy), blk, 0, stream>>>(AHL, flags, 0, W1T, Fb,
                                                     kN, 512, 512, al1f, ar1f, elb, erb);
    gat_agg<true, true, 1><<<dim3(ga), blk, 0, stream>>>(Fb, elb, erb, off, ss,
                                                         AHL, b1f, AHL);

    // 5) Layer 2 (residual, no act) + fused head-mean bf16
    gemm_mfma<true><<<dim3(4, gy), blk, 0, stream>>>(AHL, flags, 0, W2T, Fb,
                                                     kN, 512, 512, al2f, ar2f, elb, erb);
    gat_agg<true, false, 2><<<dim3(ga), blk, 0, stream>>>(Fb, elb, erb, off, ss,
                                                          AHL, b2f_, MHb);

    // 6) PQb (bf16) = head-mean @ [Wm0_top | Wm0_bot], K=128  (PQb overlays Fb)
    gemm_mfma<false><<<dim3(2, gy), blk, 0, stream>>>(MHb, flags, 0, PQT, PQb,
                                                      kN, 256, 128,
                                                      nullptr, nullptr, nullptr, nullptr);

    // 7) LDS-free edge MLP + sigmoid
    edge_mfma<<<dim3(kE / 64), blk, 0, stream>>>(PQb, bm0f, Wm1T, bm1f, wm2f, bm2f,
                                                 ss, dpos, eid, d_out, flags);
}